// Round 1
// baseline (512.227 us; speedup 1.0000x reference)
//
#include <hip/hip_runtime.h>

#define NCLS 64
#define DIM 256
#define ACC_FLOATS (NCLS * DIM + NCLS)   // 16448: sums[64][256] then counts[64]
#define MAIN_BLOCKS 512
#define MAIN_THREADS 1024

// ---------------- main pass: normalize rows, accumulate per-class sums ----------------
__global__ __launch_bounds__(MAIN_THREADS) void comp_main(
    const float* __restrict__ emb, const int* __restrict__ labels, int N,
    float* __restrict__ acc, float* __restrict__ partials /* nullptr => atomic flush */)
{
    __shared__ float lsum[NCLS * DIM];   // 64 KB
    __shared__ float lcnt[NCLS];

    const int tid = threadIdx.x;
    for (int i = tid; i < NCLS * DIM; i += MAIN_THREADS) lsum[i] = 0.0f;
    if (tid < NCLS) lcnt[tid] = 0.0f;
    __syncthreads();

    const int lane  = tid & 63;
    const int gwave = (int)((blockIdx.x * MAIN_THREADS + tid) >> 6);
    const int nwave = (int)((gridDim.x * MAIN_THREADS) >> 6);

    for (int row = gwave; row < N; row += nwave) {
        const float* r = emb + (size_t)row * DIM;
        // lane l handles elements l, l+64, l+128, l+192 -> LDS bank = l%32 (2-way, free)
        float x0 = r[lane];
        float x1 = r[lane + 64];
        float x2 = r[lane + 128];
        float x3 = r[lane + 192];
        float ss = x0 * x0 + x1 * x1 + x2 * x2 + x3 * x3;
        #pragma unroll
        for (int off = 32; off > 0; off >>= 1) ss += __shfl_xor(ss, off, 64);
        float inv = 1.0f / fmaxf(sqrtf(ss), 1e-12f);

        int c = labels[row];                 // wave-uniform (row is wave-uniform)
        float* b = &lsum[c * DIM];
        atomicAdd(&b[lane],        x0 * inv);
        atomicAdd(&b[lane + 64],   x1 * inv);
        atomicAdd(&b[lane + 128],  x2 * inv);
        atomicAdd(&b[lane + 192],  x3 * inv);
        if (lane == 0) atomicAdd(&lcnt[c], 1.0f);
    }
    __syncthreads();

    if (partials != nullptr) {
        float* p = partials + (size_t)blockIdx.x * ACC_FLOATS;
        for (int i = tid; i < NCLS * DIM; i += MAIN_THREADS) p[i] = lsum[i];
        if (tid < NCLS) p[NCLS * DIM + tid] = lcnt[tid];
    } else {
        for (int i = tid; i < NCLS * DIM; i += MAIN_THREADS)
            atomicAdd(&acc[i], lsum[i]);
        if (tid < NCLS) atomicAdd(&acc[NCLS * DIM + tid], lcnt[tid]);
    }
}

// ---------------- tree-reduce the per-block partials into acc ----------------
__global__ void comp_reduce(const float* __restrict__ partials, float* __restrict__ acc, int B)
{
    int e = blockIdx.x * blockDim.x + threadIdx.x;
    if (e >= ACC_FLOATS) return;
    float s = 0.0f;
    for (int b = 0; b < B; ++b)
        s += partials[(size_t)b * ACC_FLOATS + e];   // coalesced across threads
    acc[e] = s;
}

// ---------------- finalize: per-class loss from sums & counts ----------------
__global__ void comp_finalize(const float* __restrict__ acc, const int* __restrict__ epoch,
                              float* __restrict__ out)
{
    __shared__ float cls_loss[NCLS];
    __shared__ float cls_valid[NCLS];

    const int tid = threadIdx.x;          // 256 threads
    const int c = tid >> 2;
    const int q = tid & 3;

    const float* row = acc + c * DIM + q * 64;
    float s2 = 0.0f;
    #pragma unroll 8
    for (int d = 0; d < 64; ++d) { float v = row[d]; s2 += v * v; }
    // combine the 4 quarter-partials (lanes 4c..4c+3 are in the same wave)
    s2 += __shfl_xor(s2, 1, 64);
    s2 += __shfl_xor(s2, 2, 64);

    if (q == 0) {
        float cnt  = acc[NCLS * DIM + c];
        float invc = 1.0f / fmaxf(cnt, 1.0f);
        float cn   = sqrtf(s2) * invc;                 // ||center_raw||
        float dot  = s2 * invc / fmaxf(cn, 1e-12f);    // dot(sums, centers) per class
        float pcs  = cnt - dot;                        // sum over class of (1 - sim)
        bool  valid = cnt > 1.0f;
        cls_loss[c]  = valid ? pcs * invc : 0.0f;
        cls_valid[c] = valid ? 1.0f : 0.0f;
    }
    __syncthreads();

    if (tid < 64) {
        float sl = cls_loss[tid];
        float nv = cls_valid[tid];
        #pragma unroll
        for (int off = 32; off > 0; off >>= 1) {
            sl += __shfl_xor(sl, off, 64);
            nv += __shfl_xor(nv, off, 64);
        }
        if (tid == 0) {
            float res = (nv > 0.0f) ? (sl / fmaxf(nv, 1.0f)) : 0.0f;
            if (epoch[0] < 1) res = 0.0f;   // START guard
            out[0] = res;
        }
    }
}

extern "C" void kernel_launch(void* const* d_in, const int* in_sizes, int n_in,
                              void* d_out, int out_size, void* d_ws, size_t ws_size,
                              hipStream_t stream)
{
    const float* emb    = (const float*)d_in[0];
    const int*   labels = (const int*)d_in[1];
    const int*   epoch  = (const int*)d_in[2];
    float*       out    = (float*)d_out;

    const int N = in_sizes[0] / DIM;

    const size_t accBytes  = (size_t)ACC_FLOATS * sizeof(float);
    const size_t accPad    = (accBytes + 255) & ~(size_t)255;
    const size_t partBytes = (size_t)MAIN_BLOCKS * ACC_FLOATS * sizeof(float);

    float* acc = (float*)d_ws;
    float* partials = nullptr;
    const bool usePart = (ws_size >= accPad + partBytes);
    if (usePart) {
        partials = (float*)((char*)d_ws + accPad);
    } else {
        hipMemsetAsync(d_ws, 0, accBytes, stream);   // atomic path needs zeroed acc
    }

    comp_main<<<MAIN_BLOCKS, MAIN_THREADS, 0, stream>>>(emb, labels, N, acc, partials);
    if (usePart) {
        comp_reduce<<<(ACC_FLOATS + 255) / 256, 256, 0, stream>>>(partials, acc, MAIN_BLOCKS);
    }
    comp_finalize<<<1, 256, 0, stream>>>(acc, epoch, out);
}

// Round 2
// 358.959 us; speedup vs baseline: 1.4270x; 1.4270x over previous
//
#include <hip/hip_runtime.h>

#define NCLS 64
#define DIM 256
#define ACC_FLOATS (NCLS * DIM + NCLS)   // 16448: sums[64][256] then counts[64]
#define MAIN_BLOCKS 512
#define MAIN_THREADS 1024
#define RB 4                              // rows per wave per iteration
#define RED_CHUNKS 8

// Canonical gfx9 wave64 sum via DPP (VALU pipe, no LDS traffic).
// Result (full 64-lane sum) returned uniform via readlane(63).
__device__ __forceinline__ float wave_sum64(float f) {
    int t;
    t = __builtin_amdgcn_update_dpp(0, __float_as_int(f), 0x111, 0xf, 0xf, false); f += __int_as_float(t); // row_shr:1
    t = __builtin_amdgcn_update_dpp(0, __float_as_int(f), 0x112, 0xf, 0xf, false); f += __int_as_float(t); // row_shr:2
    t = __builtin_amdgcn_update_dpp(0, __float_as_int(f), 0x114, 0xf, 0xe, false); f += __int_as_float(t); // row_shr:4
    t = __builtin_amdgcn_update_dpp(0, __float_as_int(f), 0x118, 0xf, 0xc, false); f += __int_as_float(t); // row_shr:8
    t = __builtin_amdgcn_update_dpp(0, __float_as_int(f), 0x142, 0xa, 0xf, false); f += __int_as_float(t); // row_bcast:15
    t = __builtin_amdgcn_update_dpp(0, __float_as_int(f), 0x143, 0xc, 0xf, false); f += __int_as_float(t); // row_bcast:31
    return __int_as_float(__builtin_amdgcn_readlane(__float_as_int(f), 63));
}

// ---------------- main pass: normalize rows, accumulate per-class sums ----------------
__global__ __launch_bounds__(MAIN_THREADS, 8) void comp_main(
    const float* __restrict__ emb, const int* __restrict__ labels, int N,
    float* __restrict__ acc, float* __restrict__ partials /* nullptr => atomic flush */)
{
    __shared__ float lsum[NCLS * DIM];   // 64 KB -> 2 blocks/CU
    __shared__ float lcnt[NCLS];

    const int tid = threadIdx.x;
    for (int i = tid; i < NCLS * DIM; i += MAIN_THREADS) lsum[i] = 0.0f;
    if (tid < NCLS) lcnt[tid] = 0.0f;
    __syncthreads();

    const int lane  = tid & 63;
    const int gwave = (int)((blockIdx.x * MAIN_THREADS + tid) >> 6);
    const int nwave = (int)((gridDim.x * MAIN_THREADS) >> 6);

    const int nbatch = N / RB;
    for (int b0 = gwave; b0 < nbatch; b0 += nwave) {
        const int base = b0 * RB;
        const int4 lb = *reinterpret_cast<const int4*>(labels + base);  // wave-broadcast 16B
        const float* r0 = emb + (size_t)base * DIM;

        float x[RB][4];
        #pragma unroll
        for (int r = 0; r < RB; ++r) {
            const float* rr = r0 + (size_t)r * DIM;
            x[r][0] = rr[lane];
            x[r][1] = rr[lane + 64];
            x[r][2] = rr[lane + 128];
            x[r][3] = rr[lane + 192];
        }
        float inv[RB];
        #pragma unroll
        for (int r = 0; r < RB; ++r) {
            float ss = x[r][0]*x[r][0] + x[r][1]*x[r][1] + x[r][2]*x[r][2] + x[r][3]*x[r][3];
            float s  = wave_sum64(ss);
            inv[r] = 1.0f / fmaxf(sqrtf(s), 1e-12f);
        }
        #pragma unroll
        for (int r = 0; r < RB; ++r) {
            const int c = (r == 0) ? lb.x : (r == 1) ? lb.y : (r == 2) ? lb.z : lb.w;
            float* b = &lsum[c * DIM];
            atomicAdd(&b[lane],        x[r][0] * inv[r]);
            atomicAdd(&b[lane + 64],   x[r][1] * inv[r]);
            atomicAdd(&b[lane + 128],  x[r][2] * inv[r]);
            atomicAdd(&b[lane + 192],  x[r][3] * inv[r]);
        }
        // counts: lanes 0..3 each add one row's count (static selects, no scratch array)
        int myc = lb.x;
        myc = (lane == 1) ? lb.y : myc;
        myc = (lane == 2) ? lb.z : myc;
        myc = (lane == 3) ? lb.w : myc;
        if (lane < RB) atomicAdd(&lcnt[myc], 1.0f);
    }
    // tail rows (N % RB != 0) — generic guard
    for (int row = nbatch * RB + gwave; row < N; row += nwave) {
        const float* rr = emb + (size_t)row * DIM;
        float x0 = rr[lane], x1 = rr[lane + 64], x2 = rr[lane + 128], x3 = rr[lane + 192];
        float s = wave_sum64(x0*x0 + x1*x1 + x2*x2 + x3*x3);
        float inv = 1.0f / fmaxf(sqrtf(s), 1e-12f);
        int c = labels[row];
        float* b = &lsum[c * DIM];
        atomicAdd(&b[lane],       x0 * inv);
        atomicAdd(&b[lane + 64],  x1 * inv);
        atomicAdd(&b[lane + 128], x2 * inv);
        atomicAdd(&b[lane + 192], x3 * inv);
        if (lane == 0) atomicAdd(&lcnt[c], 1.0f);
    }
    __syncthreads();

    if (partials != nullptr) {
        float* p = partials + (size_t)blockIdx.x * ACC_FLOATS;
        for (int i = tid; i < NCLS * DIM; i += MAIN_THREADS) p[i] = lsum[i];
        if (tid < NCLS) p[NCLS * DIM + tid] = lcnt[tid];
    } else {
        for (int i = tid; i < NCLS * DIM; i += MAIN_THREADS)
            atomicAdd(&acc[i], lsum[i]);
        if (tid < NCLS) atomicAdd(&acc[NCLS * DIM + tid], lcnt[tid]);
    }
}

// ---------------- 2-stage tree-reduce of per-block partials ----------------
__global__ void comp_reduce1(const float* __restrict__ partials, float* __restrict__ acc2)
{
    int e = blockIdx.x * blockDim.x + threadIdx.x;
    if (e >= ACC_FLOATS) return;
    const int per = MAIN_BLOCKS / RED_CHUNKS;  // 64
    const float* p = partials + (size_t)blockIdx.y * per * ACC_FLOATS + e;
    float s = 0.0f;
    #pragma unroll 8
    for (int b = 0; b < per; ++b) s += p[(size_t)b * ACC_FLOATS];
    acc2[(size_t)blockIdx.y * ACC_FLOATS + e] = s;
}

__global__ void comp_reduce2(const float* __restrict__ acc2, float* __restrict__ acc)
{
    int e = blockIdx.x * blockDim.x + threadIdx.x;
    if (e >= ACC_FLOATS) return;
    float s = 0.0f;
    #pragma unroll
    for (int k = 0; k < RED_CHUNKS; ++k) s += acc2[(size_t)k * ACC_FLOATS + e];
    acc[e] = s;
}

// ---------------- finalize: per-class loss from sums & counts ----------------
__global__ void comp_finalize(const float* __restrict__ acc, const int* __restrict__ epoch,
                              float* __restrict__ out)
{
    __shared__ float cls_loss[NCLS];
    __shared__ float cls_valid[NCLS];

    const int tid = threadIdx.x;          // 256 threads
    const int c = tid >> 2;
    const int q = tid & 3;

    const float* row = acc + c * DIM + q * 64;
    float s2 = 0.0f;
    #pragma unroll 8
    for (int d = 0; d < 64; ++d) { float v = row[d]; s2 += v * v; }
    s2 += __shfl_xor(s2, 1, 64);
    s2 += __shfl_xor(s2, 2, 64);

    if (q == 0) {
        float cnt  = acc[NCLS * DIM + c];
        float invc = 1.0f / fmaxf(cnt, 1.0f);
        float cn   = sqrtf(s2) * invc;                 // ||center_raw||
        float dot  = s2 * invc / fmaxf(cn, 1e-12f);    // dot(sums, centers) per class
        float pcs  = cnt - dot;                        // sum over class of (1 - sim)
        bool  valid = cnt > 1.0f;
        cls_loss[c]  = valid ? pcs * invc : 0.0f;
        cls_valid[c] = valid ? 1.0f : 0.0f;
    }
    __syncthreads();

    if (tid < 64) {
        float sl = cls_loss[tid];
        float nv = cls_valid[tid];
        #pragma unroll
        for (int off = 32; off > 0; off >>= 1) {
            sl += __shfl_xor(sl, off, 64);
            nv += __shfl_xor(nv, off, 64);
        }
        if (tid == 0) {
            float res = (nv > 0.0f) ? (sl / fmaxf(nv, 1.0f)) : 0.0f;
            if (epoch[0] < 1) res = 0.0f;   // START guard
            out[0] = res;
        }
    }
}

extern "C" void kernel_launch(void* const* d_in, const int* in_sizes, int n_in,
                              void* d_out, int out_size, void* d_ws, size_t ws_size,
                              hipStream_t stream)
{
    const float* emb    = (const float*)d_in[0];
    const int*   labels = (const int*)d_in[1];
    const int*   epoch  = (const int*)d_in[2];
    float*       out    = (float*)d_out;

    const int N = in_sizes[0] / DIM;

    const size_t accBytes  = (size_t)ACC_FLOATS * sizeof(float);
    const size_t accPad    = (accBytes + 255) & ~(size_t)255;
    const size_t acc2Bytes = (size_t)RED_CHUNKS * ACC_FLOATS * sizeof(float);
    const size_t acc2Pad   = (acc2Bytes + 255) & ~(size_t)255;
    const size_t partBytes = (size_t)MAIN_BLOCKS * ACC_FLOATS * sizeof(float);

    float* acc = (float*)d_ws;
    float* acc2 = (float*)((char*)d_ws + accPad);
    float* partials = nullptr;
    const bool usePart = (ws_size >= accPad + acc2Pad + partBytes);
    if (usePart) {
        partials = (float*)((char*)d_ws + accPad + acc2Pad);
    } else {
        hipMemsetAsync(d_ws, 0, accBytes, stream);   // atomic path needs zeroed acc
    }

    comp_main<<<MAIN_BLOCKS, MAIN_THREADS, 0, stream>>>(emb, labels, N, acc, partials);
    if (usePart) {
        dim3 g1((ACC_FLOATS + 255) / 256, RED_CHUNKS);
        comp_reduce1<<<g1, 256, 0, stream>>>(partials, acc2);
        comp_reduce2<<<(ACC_FLOATS + 255) / 256, 256, 0, stream>>>(acc2, acc);
    }
    comp_finalize<<<1, 256, 0, stream>>>(acc, epoch, out);
}

// Round 3
// 120.365 us; speedup vs baseline: 4.2556x; 2.9822x over previous
//
#include <hip/hip_runtime.h>

#define NCLS 64
#define DIM 256
#define ACC_FLOATS (NCLS * DIM + NCLS)   // 16448: sums[64][256] then counts[64]
#define MAIN_BLOCKS 512
#define MAIN_THREADS 1024
#define RPI 8                             // rows per wave per iteration (2 groups of 4)
#define RED_CHUNKS 8

// DPP move (VALU pipe): returns src shuffled by CTRL, all rows/banks enabled.
template<int CTRL>
__device__ __forceinline__ float dpp_mov(float x) {
    return __int_as_float(__builtin_amdgcn_update_dpp(
        0, __float_as_int(x), CTRL, 0xf, 0xf, true));
}

// Sum across the 16-lane DPP row (lanes with same lane>>4 get the same result).
// quad butterfly (xor1, xor2) then combine the 4 quad-sums via row rotates.
__device__ __forceinline__ float row16_sum(float ss) {
    ss += dpp_mov<0xB1>(ss);    // quad_perm [1,0,3,2]  (xor 1)
    ss += dpp_mov<0x4E>(ss);    // quad_perm [2,3,0,1]  (xor 2)
    ss = ss + dpp_mov<0x124>(ss) + dpp_mov<0x128>(ss) + dpp_mov<0x12C>(ss); // ror 4,8,12
    return ss;
}

// ---------------- main pass: normalize rows, accumulate per-class sums ----------------
__global__ __launch_bounds__(MAIN_THREADS, 8) void comp_main(
    const float* __restrict__ emb, const int* __restrict__ labels, int N,
    float* __restrict__ acc2 /* chunk-0 target for atomic fallback */,
    float* __restrict__ partials /* nullptr => atomic flush */)
{
    __shared__ float lsum[NCLS * DIM];   // 64 KB -> 2 blocks/CU
    __shared__ float lcnt[NCLS];

    const int tid = threadIdx.x;
    for (int i = tid; i < NCLS * DIM; i += MAIN_THREADS) lsum[i] = 0.0f;
    if (tid < NCLS) lcnt[tid] = 0.0f;
    __syncthreads();

    const int lane = tid & 63;
    const int r    = lane >> 4;   // row within 4-row group
    const int m    = lane & 15;   // float4 chunk within row
    const int gwave = blockIdx.x * (MAIN_THREADS / 64) + (tid >> 6);
    const int nwave = gridDim.x * (MAIN_THREADS / 64);
    const int nbatch = N / RPI;

    for (int b = gwave; b < nbatch; b += nwave) {
        const int base = b * RPI;
        const int4 lb0 = *reinterpret_cast<const int4*>(labels + base);
        const int4 lb1 = *reinterpret_cast<const int4*>(labels + base + 4);
        // one dwordx4 per lane per group: wave covers 4 full rows per load
        const float4 v0 = *reinterpret_cast<const float4*>(emb + (size_t)(base + r) * DIM + 4 * m);
        const float4 v1 = *reinterpret_cast<const float4*>(emb + (size_t)(base + 4 + r) * DIM + 4 * m);

        {   // group 0: rows base .. base+3
            float ss = row16_sum(v0.x * v0.x + v0.y * v0.y + v0.z * v0.z + v0.w * v0.w);
            float inv = 1.0f / fmaxf(sqrtf(ss), 1e-12f);
            int c = (r == 0) ? lb0.x : (r == 1) ? lb0.y : (r == 2) ? lb0.z : lb0.w;
            float* bb = &lsum[c * DIM + 4 * m];
            atomicAdd(&bb[0], v0.x * inv);
            atomicAdd(&bb[1], v0.y * inv);
            atomicAdd(&bb[2], v0.z * inv);
            atomicAdd(&bb[3], v0.w * inv);
            if (m == 0) atomicAdd(&lcnt[c], 1.0f);
        }
        {   // group 1: rows base+4 .. base+7
            float ss = row16_sum(v1.x * v1.x + v1.y * v1.y + v1.z * v1.z + v1.w * v1.w);
            float inv = 1.0f / fmaxf(sqrtf(ss), 1e-12f);
            int c = (r == 0) ? lb1.x : (r == 1) ? lb1.y : (r == 2) ? lb1.z : lb1.w;
            float* bb = &lsum[c * DIM + 4 * m];
            atomicAdd(&bb[0], v1.x * inv);
            atomicAdd(&bb[1], v1.y * inv);
            atomicAdd(&bb[2], v1.z * inv);
            atomicAdd(&bb[3], v1.w * inv);
            if (m == 0) atomicAdd(&lcnt[c], 1.0f);
        }
    }

    // tail (not hit for N % 8 == 0, kept for generality): one row per wave
    for (int row = nbatch * RPI + gwave; row < N; row += nwave) {
        const float4 v = *reinterpret_cast<const float4*>(emb + (size_t)row * DIM + 4 * m);
        float ss = row16_sum(v.x * v.x + v.y * v.y + v.z * v.z + v.w * v.w);
        float inv = 1.0f / fmaxf(sqrtf(ss), 1e-12f);
        if (r == 0) {   // groups 1..3 hold duplicate chunks; only group 0 commits
            int c = labels[row];
            float* bb = &lsum[c * DIM + 4 * m];
            atomicAdd(&bb[0], v.x * inv);
            atomicAdd(&bb[1], v.y * inv);
            atomicAdd(&bb[2], v.z * inv);
            atomicAdd(&bb[3], v.w * inv);
            if (m == 0) atomicAdd(&lcnt[c], 1.0f);
        }
    }
    __syncthreads();

    if (partials != nullptr) {
        float* p = partials + (size_t)blockIdx.x * ACC_FLOATS;
        for (int i = tid; i < NCLS * DIM; i += MAIN_THREADS) p[i] = lsum[i];
        if (tid < NCLS) p[NCLS * DIM + tid] = lcnt[tid];
    } else {
        for (int i = tid; i < NCLS * DIM; i += MAIN_THREADS)
            atomicAdd(&acc2[i], lsum[i]);
        if (tid < NCLS) atomicAdd(&acc2[NCLS * DIM + tid], lcnt[tid]);
    }
}

// ---------------- stage-1 tree-reduce: 512 partials -> 8 chunks ----------------
__global__ void comp_reduce1(const float* __restrict__ partials, float* __restrict__ acc2)
{
    int e = blockIdx.x * blockDim.x + threadIdx.x;
    if (e >= ACC_FLOATS) return;
    const int per = MAIN_BLOCKS / RED_CHUNKS;  // 64
    const float* p = partials + (size_t)blockIdx.y * per * ACC_FLOATS + e;
    float s = 0.0f;
    #pragma unroll 8
    for (int b = 0; b < per; ++b) s += p[(size_t)b * ACC_FLOATS];
    acc2[(size_t)blockIdx.y * ACC_FLOATS + e] = s;
}

// ---------------- finalize: fold 8 chunks + per-class loss ----------------
__global__ void comp_finalize(const float* __restrict__ acc2, const int* __restrict__ epoch,
                              float* __restrict__ out)
{
    __shared__ float cls_loss[NCLS];
    __shared__ float cls_valid[NCLS];

    const int tid = threadIdx.x;          // 256 threads
    const int c = tid >> 2;
    const int q = tid & 3;

    float s2 = 0.0f;
    #pragma unroll 4
    for (int d = 0; d < 64; ++d) {
        float v = 0.0f;
        #pragma unroll
        for (int k = 0; k < RED_CHUNKS; ++k)
            v += acc2[(size_t)k * ACC_FLOATS + c * DIM + q * 64 + d];
        s2 += v * v;
    }
    s2 += __shfl_xor(s2, 1, 64);
    s2 += __shfl_xor(s2, 2, 64);

    if (q == 0) {
        float cnt = 0.0f;
        #pragma unroll
        for (int k = 0; k < RED_CHUNKS; ++k)
            cnt += acc2[(size_t)k * ACC_FLOATS + NCLS * DIM + c];
        float invc = 1.0f / fmaxf(cnt, 1.0f);
        float cn   = sqrtf(s2) * invc;                 // ||center_raw||
        float dot  = s2 * invc / fmaxf(cn, 1e-12f);    // dot(sums, centers) per class
        float pcs  = cnt - dot;                        // sum over class of (1 - sim)
        bool  valid = cnt > 1.0f;
        cls_loss[c]  = valid ? pcs * invc : 0.0f;
        cls_valid[c] = valid ? 1.0f : 0.0f;
    }
    __syncthreads();

    if (tid < 64) {
        float sl = cls_loss[tid];
        float nv = cls_valid[tid];
        #pragma unroll
        for (int off = 32; off > 0; off >>= 1) {
            sl += __shfl_xor(sl, off, 64);
            nv += __shfl_xor(nv, off, 64);
        }
        if (tid == 0) {
            float res = (nv > 0.0f) ? (sl / fmaxf(nv, 1.0f)) : 0.0f;
            if (epoch[0] < 1) res = 0.0f;   // START guard
            out[0] = res;
        }
    }
}

extern "C" void kernel_launch(void* const* d_in, const int* in_sizes, int n_in,
                              void* d_out, int out_size, void* d_ws, size_t ws_size,
                              hipStream_t stream)
{
    const float* emb    = (const float*)d_in[0];
    const int*   labels = (const int*)d_in[1];
    const int*   epoch  = (const int*)d_in[2];
    float*       out    = (float*)d_out;

    const int N = in_sizes[0] / DIM;

    const size_t acc2Bytes = (size_t)RED_CHUNKS * ACC_FLOATS * sizeof(float);
    const size_t acc2Pad   = (acc2Bytes + 255) & ~(size_t)255;
    const size_t partBytes = (size_t)MAIN_BLOCKS * ACC_FLOATS * sizeof(float);

    float* acc2 = (float*)d_ws;
    float* partials = nullptr;
    const bool usePart = (ws_size >= acc2Pad + partBytes);
    if (usePart) {
        partials = (float*)((char*)d_ws + acc2Pad);
    } else {
        hipMemsetAsync(d_ws, 0, acc2Bytes, stream);  // atomic path: zero all chunks
    }

    comp_main<<<MAIN_BLOCKS, MAIN_THREADS, 0, stream>>>(emb, labels, N, acc2, partials);
    if (usePart) {
        dim3 g1((ACC_FLOATS + 255) / 256, RED_CHUNKS);
        comp_reduce1<<<g1, 256, 0, stream>>>(partials, acc2);
    }
    comp_finalize<<<1, 256, 0, stream>>>(acc2, epoch, out);
}

// Round 4
// 62.135 us; speedup vs baseline: 8.2438x; 1.9372x over previous
//
#include <hip/hip_runtime.h>

#define CLS   64
#define DIM   256
#define HB    256          // histogram / scatter blocks
#define HT    256          // their threads
#define PARTS 8            // reduce blocks per class

// ---- wave64 sum via DPP (VALU pipe); result uniform across all lanes ----
__device__ __forceinline__ float wave_sum64(float f) {
    int t;
    t = __builtin_amdgcn_update_dpp(0, __float_as_int(f), 0x111, 0xf, 0xf, false); f += __int_as_float(t); // row_shr:1
    t = __builtin_amdgcn_update_dpp(0, __float_as_int(f), 0x112, 0xf, 0xf, false); f += __int_as_float(t); // row_shr:2
    t = __builtin_amdgcn_update_dpp(0, __float_as_int(f), 0x114, 0xf, 0xe, false); f += __int_as_float(t); // row_shr:4
    t = __builtin_amdgcn_update_dpp(0, __float_as_int(f), 0x118, 0xf, 0xc, false); f += __int_as_float(t); // row_shr:8
    t = __builtin_amdgcn_update_dpp(0, __float_as_int(f), 0x142, 0xa, 0xf, false); f += __int_as_float(t); // row_bcast:15
    t = __builtin_amdgcn_update_dpp(0, __float_as_int(f), 0x143, 0xc, 0xf, false); f += __int_as_float(t); // row_bcast:31
    return __int_as_float(__builtin_amdgcn_readlane(__float_as_int(f), 63));
}

// ---- S1: per-block label histogram -> hist[HB][CLS] ----
__global__ __launch_bounds__(HT) void k_hist(const int* __restrict__ labels, int N,
                                             int* __restrict__ hist)
{
    __shared__ int h[CLS];
    if (threadIdx.x < CLS) h[threadIdx.x] = 0;
    __syncthreads();
    const int chunk = (N + gridDim.x - 1) / gridDim.x;
    const int s = blockIdx.x * chunk;
    const int e = min(N, s + chunk);
    for (int i = s + threadIdx.x; i < e; i += blockDim.x)
        atomicAdd(&h[labels[i]], 1);
    __syncthreads();
    if (threadIdx.x < CLS) hist[blockIdx.x * CLS + threadIdx.x] = h[threadIdx.x];
}

// ---- S2: per-class exclusive scan over the HB block-counts (in place) + totals ----
__global__ __launch_bounds__(HB) void k_scan(int* __restrict__ hist, int* __restrict__ classTot)
{
    __shared__ int a[HB], b[HB];
    const int c = blockIdx.x;     // class
    const int t = threadIdx.x;    // hist row (source block)
    const int v = hist[t * CLS + c];
    a[t] = v;
    __syncthreads();
    int* src = a; int* dst = b;
    for (int off = 1; off < HB; off <<= 1) {
        dst[t] = src[t] + ((t >= off) ? src[t - off] : 0);
        __syncthreads();
        int* tmp = src; src = dst; dst = tmp;
    }
    hist[t * CLS + c] = src[t] - v;            // exclusive prefix
    if (t == HB - 1) classTot[c] = src[t];     // inclusive total
}

// ---- S3: scatter row indices into class-ordered bucket ----
__global__ __launch_bounds__(HT) void k_scatter(const int* __restrict__ labels, int N,
                                                const int* __restrict__ histEx,
                                                const int* __restrict__ classTot,
                                                int* __restrict__ bucket)
{
    __shared__ int cstart[CLS];
    __shared__ int cur[CLS];
    if (threadIdx.x == 0) {
        int acc = 0;
        for (int j = 0; j < CLS; ++j) { cstart[j] = acc; acc += classTot[j]; }
    }
    __syncthreads();
    if (threadIdx.x < CLS)
        cur[threadIdx.x] = cstart[threadIdx.x] + histEx[blockIdx.x * CLS + threadIdx.x];
    __syncthreads();
    const int chunk = (N + gridDim.x - 1) / gridDim.x;
    const int s = blockIdx.x * chunk;
    const int e = min(N, s + chunk);
    for (int i = s + threadIdx.x; i < e; i += blockDim.x) {
        int c = labels[i];
        int slot = atomicAdd(&cur[c], 1);      // order within class irrelevant (sum)
        bucket[slot] = i;
    }
}

// ---- S4: dense per-class reduction, register accumulators, zero atomics ----
__global__ __launch_bounds__(1024) void k_classsum(const float* __restrict__ emb,
                                                   const int* __restrict__ bucket,
                                                   const int* __restrict__ classTot,
                                                   float* __restrict__ partials)
{
    __shared__ int cs0, ccnt;
    __shared__ float red[16 * 260];            // padded stride 260 -> no bank conflicts
    const int c    = blockIdx.x / PARTS;
    const int part = blockIdx.x % PARTS;
    if (threadIdx.x == 0) {
        int acc = 0;
        for (int j = 0; j < c; ++j) acc += classTot[j];
        cs0 = acc;
        ccnt = classTot[c];
    }
    __syncthreads();
    const int p0 = cs0 + (int)(((long long)ccnt * part) / PARTS);
    const int p1 = cs0 + (int)(((long long)ccnt * (part + 1)) / PARTS);
    const int wid  = threadIdx.x >> 6;
    const int lane = threadIdx.x & 63;

    // one wave per row: lane l owns dims [4l, 4l+4); load = contiguous 1 KB per wave
    float4 acc4 = make_float4(0.f, 0.f, 0.f, 0.f);
    int j = p0 + wid;
    int row = (j < p1) ? bucket[j] : 0;        // software-pipelined index gather
    while (j < p1) {
        const int jn = j + 16;
        const int rown = (jn < p1) ? bucket[jn] : 0;
        const float4 v = *reinterpret_cast<const float4*>(emb + (size_t)row * DIM + 4 * lane);
        const float ss = wave_sum64(v.x * v.x + v.y * v.y + v.z * v.z + v.w * v.w);
        const float inv = 1.0f / fmaxf(sqrtf(ss), 1e-12f);
        acc4.x += v.x * inv; acc4.y += v.y * inv; acc4.z += v.z * inv; acc4.w += v.w * inv;
        j = jn; row = rown;
    }
    float* my = &red[wid * 260 + 4 * lane];
    my[0] = acc4.x; my[1] = acc4.y; my[2] = acc4.z; my[3] = acc4.w;
    __syncthreads();
    if (threadIdx.x < DIM) {
        float s = 0.f;
        #pragma unroll
        for (int w = 0; w < 16; ++w) s += red[w * 260 + threadIdx.x];
        partials[(size_t)blockIdx.x * DIM + threadIdx.x] = s;
    }
}

// ---- S5a: per-class loss from partial sums ----
__global__ __launch_bounds__(256) void k_classloss(const float* __restrict__ partials,
                                                   const int* __restrict__ classTot,
                                                   float* __restrict__ closs,
                                                   float* __restrict__ cvalid)
{
    const int c = blockIdx.x;   // 64 blocks
    const int d = threadIdx.x;  // 256 threads = one dim each
    float s = 0.f;
    #pragma unroll
    for (int p = 0; p < PARTS; ++p)
        s += partials[(size_t)(c * PARTS + p) * DIM + d];
    float w = wave_sum64(s * s);
    __shared__ float red[4];
    if ((d & 63) == 0) red[d >> 6] = w;
    __syncthreads();
    if (d == 0) {
        float s2   = red[0] + red[1] + red[2] + red[3];   // ||sums_c||^2
        float cnt  = (float)classTot[c];
        float invc = 1.0f / fmaxf(cnt, 1.0f);
        float cn   = sqrtf(s2) * invc;                    // ||center_raw||
        float dot  = s2 * invc / fmaxf(cn, 1e-12f);       // sum over class of sim
        float pcs  = cnt - dot;                           // sum over class of (1 - sim)
        bool valid = cnt > 1.0f;
        closs[c]  = valid ? pcs * invc : 0.0f;
        cvalid[c] = valid ? 1.0f : 0.0f;
    }
}

// ---- S5b: final scalar ----
__global__ void k_final(const float* __restrict__ closs, const float* __restrict__ cvalid,
                        const int* __restrict__ epoch, float* __restrict__ out)
{
    const int t = threadIdx.x;  // 64
    float sl = wave_sum64(closs[t]);
    float nv = wave_sum64(cvalid[t]);
    if (t == 0) {
        float res = (nv > 0.0f) ? (sl / fmaxf(nv, 1.0f)) : 0.0f;
        if (epoch[0] < 1) res = 0.0f;   // START guard
        out[0] = res;
    }
}

extern "C" void kernel_launch(void* const* d_in, const int* in_sizes, int n_in,
                              void* d_out, int out_size, void* d_ws, size_t ws_size,
                              hipStream_t stream)
{
    const float* emb    = (const float*)d_in[0];
    const int*   labels = (const int*)d_in[1];
    const int*   epoch  = (const int*)d_in[2];
    float*       out    = (float*)d_out;
    const int N = in_sizes[0] / DIM;

    // workspace carve-up (all regions fully overwritten each call -> no memset needed)
    char* ws = (char*)d_ws;
    size_t off = 0;
    auto carve = [&](size_t bytes) { size_t o = off; off = (off + bytes + 255) & ~(size_t)255; return o; };
    int*   hist     = (int*)  (ws + carve((size_t)HB * CLS * sizeof(int)));
    int*   classTot = (int*)  (ws + carve((size_t)CLS * sizeof(int)));
    int*   bucket   = (int*)  (ws + carve((size_t)N * sizeof(int)));
    float* partials = (float*)(ws + carve((size_t)CLS * PARTS * DIM * sizeof(float)));
    float* closs    = (float*)(ws + carve((size_t)CLS * sizeof(float)));
    float* cvalid   = (float*)(ws + carve((size_t)CLS * sizeof(float)));
    (void)ws_size;  // required ~1.6 MB; harness provides far more (observed ~1 GiB)

    k_hist    <<<HB,          HT,   0, stream>>>(labels, N, hist);
    k_scan    <<<CLS,         HB,   0, stream>>>(hist, classTot);
    k_scatter <<<HB,          HT,   0, stream>>>(labels, N, hist, classTot, bucket);
    k_classsum<<<CLS * PARTS, 1024, 0, stream>>>(emb, bucket, classTot, partials);
    k_classloss<<<CLS,        256,  0, stream>>>(partials, classTot, closs, cvalid);
    k_final   <<<1,           64,   0, stream>>>(closs, cvalid, epoch, out);
}